// Round 1
// baseline (71.749 us; speedup 1.0000x reference)
//
#include <hip/hip_runtime.h>

// NonLinearConv2d: unfold(3x3,pad1) -> per-(pixel,k,c) softplus((v-th)/D)^2 -
// softplus((v-th-VD)/D)^2 summed over k=27, scaled, then BatchNorm2d (training
// stats) over (N,H,W) per channel.
//
// Shapes: x (32,3,32,32) f32, theta (27,64) f32, gamma/beta (64) f32.
// Output (32,64,32,32) f32 = 2097152 elements.

constexpr float INV_D     = 13.333333333333334f;  // 1/0.075
constexpr float B_OFF     = 1.3333333333333333f;  // V_D/0.075
constexpr float OUT_SCALE = 5.625e-5f;            // ALPHA * R_TIA
constexpr int   NCHUNK    = 512;                  // 32768 pixels / 64

// ---------------------------------------------------------------------------
// Kernel 1: compute V_out (into d_out, used as scratch) + per-(chunk,channel)
// partial sum / sumsq for the BN statistics.
// Grid: 2048 blocks = 512 pixel-chunks x 4 channel-groups. Block: 256 threads
// = 4 waves; wave handles 64 consecutive pixels x 4 channels.
// ---------------------------------------------------------------------------
__global__ __launch_bounds__(256)
void nlc_compute(const float* __restrict__ x, const float* __restrict__ theta,
                 float* __restrict__ vout, float* __restrict__ psum,
                 float* __restrict__ psq)
{
    __shared__ float th[27 * 16];
    const int tid   = threadIdx.x;
    const int chunk = blockIdx.x >> 2;
    const int cbase = (blockIdx.x & 3) * 16;

    // stage this block's theta slice, pre-scaled by 1/DENOM
    for (int i = tid; i < 27 * 16; i += 256) {
        const int k = i >> 4, cc = i & 15;
        th[i] = theta[k * 64 + cbase + cc] * INV_D;
    }
    __syncthreads();

    const int lane = tid & 63;
    const int wv   = tid >> 6;
    const int p    = chunk * 64 + lane;   // global pixel id
    const int n    = p >> 10;
    const int hw   = p & 1023;
    const int h    = hw >> 5;
    const int w    = hw & 31;

    // 27 patch values (channel-major, then ki,kj -- matches unfold order),
    // pre-scaled by 1/DENOM, zero-padded at borders.
    float v[27];
    const float* xn = x + n * 3072;
#pragma unroll
    for (int ci = 0; ci < 3; ++ci) {
#pragma unroll
        for (int ki = 0; ki < 3; ++ki) {
#pragma unroll
            for (int kj = 0; kj < 3; ++kj) {
                const int hh = h + ki - 1;
                const int ww = w + kj - 1;
                float val = 0.f;
                if (hh >= 0 && hh < 32 && ww >= 0 && ww < 32)
                    val = xn[ci * 1024 + hh * 32 + ww];
                v[ci * 9 + ki * 3 + kj] = val * INV_D;
            }
        }
    }

#pragma unroll
    for (int i = 0; i < 4; ++i) {
        const int cl = wv * 4 + i;
        float acc = 0.f;
#pragma unroll
        for (int k = 0; k < 27; ++k) {
            const float a = v[k] - th[k * 16 + cl];
            // theta in [0,9]: for ~60% of (k,c) every lane has a < -6 ->
            // both softplus < 2.5e-3, squared diff < 1e-8 * OUT_SCALE. Skip.
            if (__all(a < -6.f)) continue;
            const float b   = a - B_OFF;
            const float spa = fmaxf(a, 0.f) + __logf(1.f + __expf(-fabsf(a)));
            const float spb = fmaxf(b, 0.f) + __logf(1.f + __expf(-fabsf(b)));
            acc = fmaf(spa, spa, acc);
            acc = fmaf(-spb, spb, acc);
        }
        const float vo = acc * OUT_SCALE;
        const int   c  = cbase + cl;
        vout[(n << 16) + (c << 10) + hw] = vo;   // NCHW, coalesced per wave

        // 64-lane tree reduction of sum and sumsq over pixels
        float s = vo, q = vo * vo;
#pragma unroll
        for (int off = 32; off > 0; off >>= 1) {
            s += __shfl_xor(s, off, 64);
            q += __shfl_xor(q, off, 64);
        }
        if (lane == 0) {
            psum[chunk * 64 + c] = s;
            psq [chunk * 64 + c] = q;
        }
    }
}

// ---------------------------------------------------------------------------
// Kernel 2: reduce the 512 partials per channel (in double), produce
// scale = gamma * rstd, shift = beta - mean * scale.
// ---------------------------------------------------------------------------
__global__ __launch_bounds__(256)
void nlc_stats(const float* __restrict__ psum, const float* __restrict__ psq,
               const float* __restrict__ gamma, const float* __restrict__ beta,
               float* __restrict__ ss)
{
    __shared__ double ls[256], lq[256];
    const int tid  = threadIdx.x;
    const int c    = tid & 63;
    const int part = tid >> 6;

    double s = 0.0, q = 0.0;
    for (int j = part; j < NCHUNK; j += 4) {
        s += (double)psum[j * 64 + c];
        q += (double)psq [j * 64 + c];
    }
    ls[tid] = s;
    lq[tid] = q;
    __syncthreads();
    if (part == 0) {
        s = ls[c] + ls[c + 64] + ls[c + 128] + ls[c + 192];
        q = lq[c] + lq[c + 64] + lq[c + 128] + lq[c + 192];
        const double inv  = 1.0 / 32768.0;
        const double mean = s * inv;
        const double var  = q * inv - mean * mean;   // biased (ddof=0)
        const float  rstd = (float)(1.0 / sqrt(var + 1e-5));
        const float  sc   = gamma[c] * rstd;
        const float  sh   = beta[c] - (float)mean * sc;
        ss[c]      = sc;
        ss[64 + c] = sh;
    }
}

// ---------------------------------------------------------------------------
// Kernel 3: in-place BN apply on d_out, float4-vectorized.
// ---------------------------------------------------------------------------
__global__ __launch_bounds__(256)
void nlc_apply(float* __restrict__ vout, const float* __restrict__ ss)
{
    const int i = blockIdx.x * 256 + threadIdx.x;      // float4 index
    const int c = (i >> 8) & 63;                       // 256 float4 per channel
    float4 vv = reinterpret_cast<const float4*>(vout)[i];
    const float sc = ss[c];
    const float sh = ss[64 + c];
    vv.x = fmaf(vv.x, sc, sh);
    vv.y = fmaf(vv.y, sc, sh);
    vv.z = fmaf(vv.z, sc, sh);
    vv.w = fmaf(vv.w, sc, sh);
    reinterpret_cast<float4*>(vout)[i] = vv;
}

extern "C" void kernel_launch(void* const* d_in, const int* in_sizes, int n_in,
                              void* d_out, int out_size, void* d_ws, size_t ws_size,
                              hipStream_t stream)
{
    const float* x     = (const float*)d_in[0];
    const float* theta = (const float*)d_in[1];
    const float* gamma = (const float*)d_in[2];
    const float* beta  = (const float*)d_in[3];
    float* out = (float*)d_out;

    float* psum = (float*)d_ws;                 // 512*64 floats
    float* psq  = psum + NCHUNK * 64;           // 512*64 floats
    float* ss   = psq  + NCHUNK * 64;           // 128 floats (scale, shift)

    nlc_compute<<<NCHUNK * 4, 256, 0, stream>>>(x, theta, out, psum, psq);
    nlc_stats  <<<1, 256, 0, stream>>>(psum, psq, gamma, beta, ss);
    nlc_apply  <<<2097152 / 4 / 256, 256, 0, stream>>>(out, ss);
}